// Round 4
// baseline (5002.468 us; speedup 1.0000x reference)
//
#include <hip/hip_runtime.h>

#define EPS 1e-5f
#define SLOPE 0.01f

// ===========================================================================
// Preprocessing: counting-sort edges by (output-range [, k]).
// S1: down pairs   key=(dst_down>>7)*27+k  rec = src | (dst&127)<<24
// S2: g pairs      key=(dst_g>>7)*27+k     rec = src | (dst&127)<<24
// S3: g transposed key=(src_g>>7)*27+k     rec = dst | (src&127)<<24
// S4: down transposed (for conv_up) key=src_down>>7
//     rec = dst_down | (src_down&127)<<16 | k<<23
// ===========================================================================
template<int WITHK>
__global__ __launch_bounds__(256) void hist_kernel(
    const int* __restrict__ scat, int E, int SH, int* __restrict__ cnt)
{
    const int k = blockIdx.y;
    const int* s = scat + (size_t)k * E;
    for (int e = blockIdx.x * 256 + threadIdx.x; e < E; e += gridDim.x * 256) {
        int key = s[e] >> SH;
        if (WITHK) key = key * 27 + k;
        atomicAdd(&cnt[key], 1);
    }
}

// 4 independent single-block scans fused into one launch (blockIdx picks).
__global__ __launch_bounds__(1024) void scan4_kernel(
    const int* c0, int n0, int* o0, int* u0,
    const int* c1, int n1, int* o1, int* u1,
    const int* c2, int n2, int* o2, int* u2,
    const int* c3, int n3, int* o3, int* u3)
{
    const int* cnt; int n; int* offs; int* cur;
    switch (blockIdx.x) {
        case 0:  cnt = c0; n = n0; offs = o0; cur = u0; break;
        case 1:  cnt = c1; n = n1; offs = o1; cur = u1; break;
        case 2:  cnt = c2; n = n2; offs = o2; cur = u2; break;
        default: cnt = c3; n = n3; offs = o3; cur = u3; break;
    }
    __shared__ int part[1024];
    const int tid = threadIdx.x;
    const int chunk = (n + 1023) >> 10;
    const int lo = min(n, tid * chunk), hi = min(n, lo + chunk);
    int s = 0;
    for (int i = lo; i < hi; ++i) s += cnt[i];
    part[tid] = s;
    __syncthreads();
    for (int d = 1; d < 1024; d <<= 1) {
        const int t = (tid >= d) ? part[tid - d] : 0;
        __syncthreads();
        part[tid] += t;
        __syncthreads();
    }
    int run = part[tid] - s;                 // exclusive prefix of this chunk
    for (int i = lo; i < hi; ++i) {
        const int cv = cnt[i];
        offs[i] = run; cur[i] = run; run += cv;
    }
    if (tid == 1023) offs[n] = run;          // total
}

template<int WITHK>
__global__ __launch_bounds__(256) void bucket_kernel(
    const int* __restrict__ gat, const int* __restrict__ scat, int E, int SH,
    int packSH, int kSH, int* __restrict__ cur, unsigned* __restrict__ recs)
{
    const int k = blockIdx.y;
    const int* g = gat + (size_t)k * E;
    const int* d = scat + (size_t)k * E;
    for (int e = blockIdx.x * 256 + threadIdx.x; e < E; e += gridDim.x * 256) {
        const int dv = d[e];
        int key = dv >> SH;
        if (WITHK) key = key * 27 + k;
        unsigned rec = (unsigned)g[e] | ((unsigned)(dv & ((1 << SH) - 1)) << packSH);
        if (!WITHK) rec |= (unsigned)k << kSH;
        const int pos = atomicAdd(&cur[key], 1);
        recs[pos] = rec;
    }
}

// ===========================================================================
// Pipelined gather conv. Block owns 128 output rows (32 KB LDS acc).
// Phases = 27*CHUNKS (k, 64-wide input-channel chunk); per phase a 64x64 W
// tile is consumed from LDS (double-buffered: next tile global->reg at phase
// start, reg->LDS after the edge loop; one barrier per phase). Each wave
// processes 8-edge groups with register prefetch of the next group's recs+x,
// so gather latency hides under the FMA block. Scatter = LDS atomicAdd
// (lane=channel, conflict-free). One plain store per output row + fused
// per-channel sum/sumsq stats.
// ===========================================================================
template<int CHUNKS>
__global__ __launch_bounds__(256) void conv_pipe(
    const float* __restrict__ x, const float* __restrict__ W,
    const unsigned* __restrict__ recs, const int* __restrict__ offs,
    float* __restrict__ outb, int Nout, float* __restrict__ st)
{
    constexpr int CIN = CHUNKS * 64;
    constexpr int PH  = 27 * CHUNKS;
    __shared__ float acc[128 * 64];      // 32 KB
    __shared__ float Wb[2][64 * 64];     // 32 KB (double buffer)
    __shared__ float xs[4][8 * 64];      // 8 KB  (8 edges per wave-group)
    __shared__ float red[512];           // 2 KB
    const int p   = blockIdx.x;
    const int tid = threadIdx.x;
    const int w   = tid >> 6;
    const int c   = tid & 63;

    const float4 z = {0.f, 0.f, 0.f, 0.f};
    for (int i = tid * 4; i < 128 * 64; i += 1024) *(float4*)&acc[i] = z;

    // stage phase-0 W tile into Wb[0]
    float4 wr0, wr1, wr2, wr3;
    {
        const float* Ws = W;
        wr0 = *(const float4*)&Ws[(0 * 256 + tid) * 4];
        wr1 = *(const float4*)&Ws[(1 * 256 + tid) * 4];
        wr2 = *(const float4*)&Ws[(2 * 256 + tid) * 4];
        wr3 = *(const float4*)&Ws[(3 * 256 + tid) * 4];
        *(float4*)&Wb[0][(0 * 256 + tid) * 4] = wr0;
        *(float4*)&Wb[0][(1 * 256 + tid) * 4] = wr1;
        *(float4*)&Wb[0][(2 * 256 + tid) * 4] = wr2;
        *(float4*)&Wb[0][(3 * 256 + tid) * 4] = wr3;
    }
    __syncthreads();

    float* xw = xs[w];
    const int* offp = offs + p * 27;

    for (int ph = 0; ph < PH; ++ph) {
        const int b = ph & 1;
        // prefetch next W tile into regs (consumed by ds_write after edge loop)
        if (ph + 1 < PH) {
            const float* Ws = W + (size_t)(ph + 1) * 4096;
            wr0 = *(const float4*)&Ws[(0 * 256 + tid) * 4];
            wr1 = *(const float4*)&Ws[(1 * 256 + tid) * 4];
            wr2 = *(const float4*)&Ws[(2 * 256 + tid) * 4];
            wr3 = *(const float4*)&Ws[(3 * 256 + tid) * 4];
        }
        const int  xoff = (ph % CHUNKS) * 64;
        const int  kk   = ph / CHUNKS;
        const int  lo = offp[kk], hi = offp[kk + 1];
        const float* Wp = Wb[b];

        int e0 = lo + w * 8;
        if (e0 < hi) {
            const int last = hi - 1;
            unsigned q0 = recs[e0];
            unsigned q1 = recs[min(e0 + 1, last)];
            unsigned q2 = recs[min(e0 + 2, last)];
            unsigned q3 = recs[min(e0 + 3, last)];
            unsigned q4 = recs[min(e0 + 4, last)];
            unsigned q5 = recs[min(e0 + 5, last)];
            unsigned q6 = recs[min(e0 + 6, last)];
            unsigned q7 = recs[min(e0 + 7, last)];
            float g0 = x[(size_t)(q0 & 0xFFFFFFu) * CIN + xoff + c];
            float g1 = x[(size_t)(q1 & 0xFFFFFFu) * CIN + xoff + c];
            float g2 = x[(size_t)(q2 & 0xFFFFFFu) * CIN + xoff + c];
            float g3 = x[(size_t)(q3 & 0xFFFFFFu) * CIN + xoff + c];
            float g4 = x[(size_t)(q4 & 0xFFFFFFu) * CIN + xoff + c];
            float g5 = x[(size_t)(q5 & 0xFFFFFFu) * CIN + xoff + c];
            float g6 = x[(size_t)(q6 & 0xFFFFFFu) * CIN + xoff + c];
            float g7 = x[(size_t)(q7 & 0xFFFFFFu) * CIN + xoff + c];
            while (e0 < hi) {
                const int ne = hi - e0;
                const unsigned d0 = q0, d1 = q1, d2 = q2, d3 = q3;
                const unsigned d4 = q4, d5 = q5, d6 = q6, d7 = q7;
                // commit current group to LDS (vmcnt wait lands here; the
                // loads have been in flight since before the previous FMA)
                xw[0 * 64 + c] = g0; xw[1 * 64 + c] = g1;
                xw[2 * 64 + c] = g2; xw[3 * 64 + c] = g3;
                xw[4 * 64 + c] = g4; xw[5 * 64 + c] = g5;
                xw[6 * 64 + c] = g6; xw[7 * 64 + c] = g7;
                const int en = e0 + 32;
                if (en < hi) {
                    const int l2 = hi - 1;
                    q0 = recs[en];
                    q1 = recs[min(en + 1, l2)];
                    q2 = recs[min(en + 2, l2)];
                    q3 = recs[min(en + 3, l2)];
                    q4 = recs[min(en + 4, l2)];
                    q5 = recs[min(en + 5, l2)];
                    q6 = recs[min(en + 6, l2)];
                    q7 = recs[min(en + 7, l2)];
                    g0 = x[(size_t)(q0 & 0xFFFFFFu) * CIN + xoff + c];
                    g1 = x[(size_t)(q1 & 0xFFFFFFu) * CIN + xoff + c];
                    g2 = x[(size_t)(q2 & 0xFFFFFFu) * CIN + xoff + c];
                    g3 = x[(size_t)(q3 & 0xFFFFFFu) * CIN + xoff + c];
                    g4 = x[(size_t)(q4 & 0xFFFFFFu) * CIN + xoff + c];
                    g5 = x[(size_t)(q5 & 0xFFFFFFu) * CIN + xoff + c];
                    g6 = x[(size_t)(q6 & 0xFFFFFFu) * CIN + xoff + c];
                    g7 = x[(size_t)(q7 & 0xFFFFFFu) * CIN + xoff + c];
                }
                __builtin_amdgcn_wave_barrier();
                float a0 = 0.f, a1 = 0.f, a2 = 0.f, a3 = 0.f;
                float a4 = 0.f, a5 = 0.f, a6 = 0.f, a7 = 0.f;
                #pragma unroll
                for (int i = 0; i < 64; i += 4) {
                    const float4 x0 = *(const float4*)&xw[0 * 64 + i];
                    const float4 x1 = *(const float4*)&xw[1 * 64 + i];
                    const float4 x2 = *(const float4*)&xw[2 * 64 + i];
                    const float4 x3 = *(const float4*)&xw[3 * 64 + i];
                    const float4 x4 = *(const float4*)&xw[4 * 64 + i];
                    const float4 x5 = *(const float4*)&xw[5 * 64 + i];
                    const float4 x6 = *(const float4*)&xw[6 * 64 + i];
                    const float4 x7 = *(const float4*)&xw[7 * 64 + i];
                    const float w0 = Wp[(i + 0) * 64 + c];
                    const float w1 = Wp[(i + 1) * 64 + c];
                    const float w2 = Wp[(i + 2) * 64 + c];
                    const float w3 = Wp[(i + 3) * 64 + c];
                    a0 = fmaf(x0.w, w3, fmaf(x0.z, w2, fmaf(x0.y, w1, fmaf(x0.x, w0, a0))));
                    a1 = fmaf(x1.w, w3, fmaf(x1.z, w2, fmaf(x1.y, w1, fmaf(x1.x, w0, a1))));
                    a2 = fmaf(x2.w, w3, fmaf(x2.z, w2, fmaf(x2.y, w1, fmaf(x2.x, w0, a2))));
                    a3 = fmaf(x3.w, w3, fmaf(x3.z, w2, fmaf(x3.y, w1, fmaf(x3.x, w0, a3))));
                    a4 = fmaf(x4.w, w3, fmaf(x4.z, w2, fmaf(x4.y, w1, fmaf(x4.x, w0, a4))));
                    a5 = fmaf(x5.w, w3, fmaf(x5.z, w2, fmaf(x5.y, w1, fmaf(x5.x, w0, a5))));
                    a6 = fmaf(x6.w, w3, fmaf(x6.z, w2, fmaf(x6.y, w1, fmaf(x6.x, w0, a6))));
                    a7 = fmaf(x7.w, w3, fmaf(x7.z, w2, fmaf(x7.y, w1, fmaf(x7.x, w0, a7))));
                }
                __builtin_amdgcn_wave_barrier();
                atomicAdd(&acc[(int)(d0 >> 24) * 64 + c], a0);
                if (ne > 1) atomicAdd(&acc[(int)(d1 >> 24) * 64 + c], a1);
                if (ne > 2) atomicAdd(&acc[(int)(d2 >> 24) * 64 + c], a2);
                if (ne > 3) atomicAdd(&acc[(int)(d3 >> 24) * 64 + c], a3);
                if (ne > 4) atomicAdd(&acc[(int)(d4 >> 24) * 64 + c], a4);
                if (ne > 5) atomicAdd(&acc[(int)(d5 >> 24) * 64 + c], a5);
                if (ne > 6) atomicAdd(&acc[(int)(d6 >> 24) * 64 + c], a6);
                if (ne > 7) atomicAdd(&acc[(int)(d7 >> 24) * 64 + c], a7);
                e0 = en;
            }
        }
        // publish next W tile and flip buffers
        if (ph + 1 < PH) {
            float* Wn = Wb[b ^ 1];
            *(float4*)&Wn[(0 * 256 + tid) * 4] = wr0;
            *(float4*)&Wn[(1 * 256 + tid) * 4] = wr1;
            *(float4*)&Wn[(2 * 256 + tid) * 4] = wr2;
            *(float4*)&Wn[(3 * 256 + tid) * 4] = wr3;
        }
        __syncthreads();
    }

    const int base = p * 128;
    for (int i = tid; i < 128 * 16; i += 256) {
        const int row = base + (i >> 4);
        if (row < Nout)
            *(float4*)&outb[(size_t)row * 64 + (i & 15) * 4] = *(const float4*)&acc[i * 4];
    }

    // fused per-channel stats (rows >= Nout are zero -> contribute nothing)
    float s = 0.f, q = 0.f;
    #pragma unroll
    for (int rr = 0; rr < 32; ++rr) {
        const float v = acc[(w * 32 + rr) * 64 + c];
        s += v;
        q = fmaf(v, v, q);
    }
    red[tid] = s; red[256 + tid] = q;
    __syncthreads();
    if (tid < 64) {
        atomicAdd(&st[c],      red[c] + red[64 + c] + red[128 + c] + red[192 + c]);
        atomicAdd(&st[64 + c], red[256 + c] + red[320 + c] + red[384 + c] + red[448 + c]);
    }
}

// ---------------------------------------------------------------------------
// Cin=1 up-conv, gather-style with register prefetch: block owns 128 fine
// rows; all of W_up in LDS. Fused per-channel stats epilogue.
// ---------------------------------------------------------------------------
__global__ __launch_bounds__(256) void conv_up_gather(
    const float* __restrict__ s1, const float* __restrict__ Wup,
    const unsigned* __restrict__ recs, const int* __restrict__ offs,
    float* __restrict__ outb, int Nout, float* __restrict__ st)
{
    __shared__ float acc[128 * 64];          // 32 KB
    __shared__ float Wl[27 * 64];            // 6.9 KB
    __shared__ float red[512];               // 2 KB
    const int p   = blockIdx.x;
    const int tid = threadIdx.x;
    const int w   = tid >> 6;
    const int c   = tid & 63;

    const float4 z = {0.f, 0.f, 0.f, 0.f};
    for (int i = tid * 4; i < 128 * 64; i += 1024) *(float4*)&acc[i] = z;
    for (int i = tid; i < 27 * 64; i += 256) Wl[i] = Wup[i];
    __syncthreads();

    const int lo = offs[p], hi = offs[p + 1];
    int e0 = lo + w * 4;
    if (e0 < hi) {
        const int last = hi - 1;
        unsigned q0 = recs[e0];
        unsigned q1 = recs[min(e0 + 1, last)];
        unsigned q2 = recs[min(e0 + 2, last)];
        unsigned q3 = recs[min(e0 + 3, last)];
        float v0 = s1[q0 & 0xFFFFu];
        float v1 = s1[q1 & 0xFFFFu];
        float v2 = s1[q2 & 0xFFFFu];
        float v3 = s1[q3 & 0xFFFFu];
        while (e0 < hi) {
            const int ne = hi - e0;
            const unsigned d0 = q0, d1 = q1, d2 = q2, d3 = q3;
            const float u0 = v0, u1 = v1, u2 = v2, u3 = v3;
            const int en = e0 + 16;
            if (en < hi) {
                const int l2 = hi - 1;
                q0 = recs[en];
                q1 = recs[min(en + 1, l2)];
                q2 = recs[min(en + 2, l2)];
                q3 = recs[min(en + 3, l2)];
                v0 = s1[q0 & 0xFFFFu];
                v1 = s1[q1 & 0xFFFFu];
                v2 = s1[q2 & 0xFFFFu];
                v3 = s1[q3 & 0xFFFFu];
            }
            atomicAdd(&acc[(int)((d0 >> 16) & 127u) * 64 + c], u0 * Wl[(int)(d0 >> 23) * 64 + c]);
            if (ne > 1) atomicAdd(&acc[(int)((d1 >> 16) & 127u) * 64 + c], u1 * Wl[(int)(d1 >> 23) * 64 + c]);
            if (ne > 2) atomicAdd(&acc[(int)((d2 >> 16) & 127u) * 64 + c], u2 * Wl[(int)(d2 >> 23) * 64 + c]);
            if (ne > 3) atomicAdd(&acc[(int)((d3 >> 16) & 127u) * 64 + c], u3 * Wl[(int)(d3 >> 23) * 64 + c]);
            e0 = en;
        }
    }
    __syncthreads();

    const int base = p * 128;
    for (int i = tid; i < 128 * 16; i += 256) {
        const int row = base + (i >> 4);
        if (row < Nout)
            *(float4*)&outb[(size_t)row * 64 + (i & 15) * 4] = *(const float4*)&acc[i * 4];
    }

    float s = 0.f, q = 0.f;
    #pragma unroll
    for (int rr = 0; rr < 32; ++rr) {
        const float v = acc[(w * 32 + rr) * 64 + c];
        s += v;
        q = fmaf(v, v, q);
    }
    red[tid] = s; red[256 + tid] = q;
    __syncthreads();
    if (tid < 64) {
        atomicAdd(&st[c],      red[c] + red[64 + c] + red[128 + c] + red[192 + c]);
        atomicAdd(&st[64 + c], red[256 + c] + red[320 + c] + red[384 + c] + red[448 + c]);
    }
}

// ---------------------------------------------------------------------------
// Cout=1 conv: acc1[dst] += dot(s[src,:64], W_sum[k,:,0]). Thread-per-edge.
// Atomic traffic only 2.7 MB -> scatter form is fine.
// ---------------------------------------------------------------------------
__global__ __launch_bounds__(256) void conv_sum_kernel(
    const float* __restrict__ s, const float* __restrict__ Wsum,
    const int* __restrict__ src, const int* __restrict__ dst,
    float* __restrict__ acc1, int E)
{
    const int k = blockIdx.y;
    __shared__ float Wl[64];
    if (threadIdx.x < 64) Wl[threadIdx.x] = Wsum[k * 64 + threadIdx.x];
    __syncthreads();
    for (int e = blockIdx.x * 256 + threadIdx.x; e < E; e += gridDim.x * 256) {
        const int si = src[(size_t)k * E + e];
        const float4* row = (const float4*)(s + (size_t)si * 64);
        float acc = 0.f;
        #pragma unroll
        for (int q = 0; q < 16; ++q) {
            const float4 v = row[q];
            acc = fmaf(v.x, Wl[q * 4 + 0], acc);
            acc = fmaf(v.y, Wl[q * 4 + 1], acc);
            acc = fmaf(v.z, Wl[q * 4 + 2], acc);
            acc = fmaf(v.w, Wl[q * 4 + 3], acc);
        }
        atomicAdd(&acc1[dst[(size_t)k * E + e]], acc);
    }
}

// ---------------------------------------------------------------------------
__global__ __launch_bounds__(256) void stats1(
    const float* __restrict__ x, int N, float* __restrict__ st)
{
    float s = 0.f, q = 0.f;
    for (int i = blockIdx.x * 256 + threadIdx.x; i < N; i += gridDim.x * 256) {
        const float v = x[i];
        s += v;
        q = fmaf(v, v, q);
    }
    __shared__ float ls[256], lq[256];
    ls[threadIdx.x] = s; lq[threadIdx.x] = q;
    __syncthreads();
    for (int off = 128; off > 0; off >>= 1) {
        if (threadIdx.x < off) {
            ls[threadIdx.x] += ls[threadIdx.x + off];
            lq[threadIdx.x] += lq[threadIdx.x + off];
        }
        __syncthreads();
    }
    if (threadIdx.x == 0) { atomicAdd(&st[0], ls[0]); atomicAdd(&st[1], lq[0]); }
}

// ---------------------------------------------------------------------------
// In-place BN + activation (ACT 0=LeakyReLU, 1=sigmoid), optional += add.
// ---------------------------------------------------------------------------
template<int ACT>
__global__ __launch_bounds__(256) void apply_bn(
    float* __restrict__ x, const float* __restrict__ st, int N, float invN,
    const float* __restrict__ gam, const float* __restrict__ bet,
    const float* __restrict__ add)
{
    __shared__ float sc[64], sh[64];
    if (threadIdx.x < 64) {
        const int c = threadIdx.x;
        const float m = st[c] * invN;
        const float v = st[64 + c] * invN - m * m;
        const float s = rsqrtf(v + EPS) * gam[c];
        sc[c] = s;
        sh[c] = bet[c] - m * s;
    }
    __syncthreads();
    const size_t n = (size_t)N * 64;
    for (size_t i = (size_t)blockIdx.x * 256 + threadIdx.x; i < n;
         i += (size_t)gridDim.x * 256) {
        const int c = (int)(i & 63);
        float y = fmaf(x[i], sc[c], sh[c]);
        if (ACT == 0) y = (y >= 0.f) ? y : SLOPE * y;
        else          y = 1.f / (1.f + __expf(-y));
        if (add) y += add[i];
        x[i] = y;
    }
}

__global__ __launch_bounds__(256) void apply_bn1(
    float* __restrict__ x, const float* __restrict__ st, int N, float invN,
    const float* __restrict__ gam, const float* __restrict__ bet)
{
    const float m  = st[0] * invN;
    const float v  = st[1] * invN - m * m;
    const float s  = rsqrtf(v + EPS) * gam[0];
    const float sh = bet[0] - m * s;
    for (int i = blockIdx.x * 256 + threadIdx.x; i < N; i += gridDim.x * 256) {
        const float y = fmaf(x[i], s, sh);
        x[i] = (y >= 0.f) ? y : SLOPE * y;
    }
}

// ---------------------------------------------------------------------------
extern "C" void kernel_launch(void* const* d_in, const int* in_sizes, int n_in,
                              void* d_out, int out_size, void* d_ws, size_t ws_size,
                              hipStream_t stream)
{
    const float* gate     = (const float*)d_in[0];
    const float* shortcut = (const float*)d_in[1];
    const int*   src_down = (const int*)d_in[2];
    const int*   dst_down = (const int*)d_in[3];
    const int*   src_g    = (const int*)d_in[4];
    const int*   dst_g    = (const int*)d_in[5];
    const float* W_sc     = (const float*)d_in[6];
    const float* W_g      = (const float*)d_in[8];
    const float* W_gu     = (const float*)d_in[10];
    const float* W_sum    = (const float*)d_in[12];
    const float* W_up     = (const float*)d_in[13];
    const float* gam_sc   = (const float*)d_in[15];
    const float* bet_sc   = (const float*)d_in[16];
    const float* gam_g    = (const float*)d_in[17];
    const float* bet_g    = (const float*)d_in[18];
    const float* gam_gu   = (const float*)d_in[19];
    const float* bet_gu   = (const float*)d_in[20];
    const float* gam_sum  = (const float*)d_in[21];
    const float* bet_sum  = (const float*)d_in[22];
    const float* gam_up   = (const float*)d_in[23];
    const float* bet_up   = (const float*)d_in[24];

    const int K   = 27;
    const int Nc  = in_sizes[0] / 128;   // 60000
    const int Nf  = in_sizes[1] / 64;    // 200000
    const int Ekd = in_sizes[2] / K;     // 40000
    const int Ekg = in_sizes[4] / K;     // 25000

    const int SHC = 7,  RC = 128;        // coarse range: 128 rows (32 KB acc)
    const int SHF = 7,  RF = 128;        // fine   range: 128 rows
    const int NRC = (Nc + RC - 1) / RC;  // 469
    const int NRF = (Nf + RF - 1) / RF;  // 1563
    const int NBC = NRC * K;             // 12663 bins per coarse set
    const int NBF = NRF;                 // 1563 bins (k folded into record)

    float* A  = (float*)d_ws;            // theta
    float* B  = A + (size_t)Nc * 64;     // phi
    float* C  = B + (size_t)Nc * 64;     // s
    float* D  = C + (size_t)Nc * 64;     // s1 (Nc floats)
    float* ST = D + Nc;                  // stats: 640 floats
    int* cnt1 = (int*)(ST + 640);
    int* cnt2 = cnt1 + NBC;
    int* cnt3 = cnt2 + NBC;
    int* cnt4 = cnt3 + NBC;
    int* off1 = cnt4 + NBF;
    int* off2 = off1 + NBC + 1;
    int* off3 = off2 + NBC + 1;
    int* off4 = off3 + NBC + 1;
    int* cur1 = off4 + NBF + 1;
    int* cur2 = cur1 + NBC;
    int* cur3 = cur2 + NBC;
    int* cur4 = cur3 + NBC;
    unsigned* rec1 = (unsigned*)(cur4 + NBF);
    unsigned* rec2 = rec1 + (size_t)K * Ekd;
    unsigned* rec3 = rec2 + (size_t)K * Ekg;
    unsigned* rec4 = rec3 + (size_t)K * Ekg;

    hipMemsetAsync(cnt1, 0, (size_t)(3 * NBC + NBF) * sizeof(int), stream);
    hipMemsetAsync(D, 0, (size_t)(Nc + 640) * sizeof(float), stream);
    float* out = (float*)d_out;

    const dim3 blk(256);
    const dim3 eg(64, K);

    // ---- build sorted edge lists (counting sort by output range [,k]) ----
    hist_kernel<1><<<eg, blk, 0, stream>>>(dst_down, Ekd, SHC, cnt1);
    hist_kernel<1><<<eg, blk, 0, stream>>>(dst_g,    Ekg, SHC, cnt2);
    hist_kernel<1><<<eg, blk, 0, stream>>>(src_g,    Ekg, SHC, cnt3);
    hist_kernel<0><<<eg, blk, 0, stream>>>(src_down, Ekd, SHF, cnt4);
    scan4_kernel<<<4, 1024, 0, stream>>>(cnt1, NBC, off1, cur1,
                                         cnt2, NBC, off2, cur2,
                                         cnt3, NBC, off3, cur3,
                                         cnt4, NBF, off4, cur4);
    bucket_kernel<1><<<eg, blk, 0, stream>>>(src_down, dst_down, Ekd, SHC, 24, 0,  cur1, rec1);
    bucket_kernel<1><<<eg, blk, 0, stream>>>(src_g,    dst_g,    Ekg, SHC, 24, 0,  cur2, rec2);
    bucket_kernel<1><<<eg, blk, 0, stream>>>(dst_g,    src_g,    Ekg, SHC, 24, 0,  cur3, rec3);
    bucket_kernel<0><<<eg, blk, 0, stream>>>(dst_down, src_down, Ekd, SHF, 16, 23, cur4, rec4);

    // theta = leaky(bn(sconv(shortcut, W_sc, src_down->dst_down)))
    conv_pipe<1><<<NRC, blk, 0, stream>>>(shortcut, W_sc, rec1, off1, A, Nc, ST + 0);
    // phi_raw = sconv(gate, W_g, src_g->dst_g)
    conv_pipe<2><<<NRC, blk, 0, stream>>>(gate, W_g, rec2, off2, B, Nc, ST + 128);

    apply_bn<0><<<1024, blk, 0, stream>>>(A, ST + 0,   Nc, 1.0f / Nc, gam_sc, bet_sc, nullptr);
    apply_bn<0><<<1024, blk, 0, stream>>>(B, ST + 128, Nc, 1.0f / Nc, gam_g,  bet_g,  nullptr);

    // phi = leaky(bn(sconv(phi, W_gu, dst_g->src_g)))  (transposed index pairs)
    conv_pipe<1><<<NRC, blk, 0, stream>>>(B, W_gu, rec3, off3, C, Nc, ST + 256);
    // s = leaky(bn(C)) + theta
    apply_bn<0><<<1024, blk, 0, stream>>>(C, ST + 256, Nc, 1.0f / Nc, gam_gu, bet_gu, A);

    // s1 = leaky(bn(sconv(s, W_sum, src_g->dst_g)))   (Cout = 1)
    conv_sum_kernel<<<dim3(32, K), blk, 0, stream>>>(C, W_sum, src_g, dst_g, D, Ekg);
    stats1<<<256, blk, 0, stream>>>(D, Nc, ST + 384);
    apply_bn1<<<256, blk, 0, stream>>>(D, ST + 384, Nc, 1.0f / Nc, gam_sum, bet_sum);

    // out = sigmoid(bn(sconv(s1, W_up, dst_down->src_down)))  (Cin = 1, fine res)
    conv_up_gather<<<NRF, blk, 0, stream>>>(D, W_up, rec4, off4, out, Nf, ST + 512);
    apply_bn<1><<<2048, blk, 0, stream>>>(out, ST + 512, Nf, 1.0f / Nf, gam_up, bet_up, nullptr);
}

// Round 5
// 1961.134 us; speedup vs baseline: 2.5508x; 2.5508x over previous
//
#include <hip/hip_runtime.h>

#define EPS 1e-5f
#define SLOPE 0.01f

// ===========================================================================
// Minimal sort (for conv_up only): bucket down-edges by fine output range.
// key = src_down>>7 ; rec = dst_down | (src_down&127)<<16 | k<<23
// (dst_down < 60000 fits 16 bits; k < 27 fits 5 bits)
// ===========================================================================
template<int WITHK>
__global__ __launch_bounds__(256) void hist_kernel(
    const int* __restrict__ scat, int E, int SH, int* __restrict__ cnt)
{
    const int k = blockIdx.y;
    const int* s = scat + (size_t)k * E;
    for (int e = blockIdx.x * 256 + threadIdx.x; e < E; e += gridDim.x * 256) {
        int key = s[e] >> SH;
        if (WITHK) key = key * 27 + k;
        atomicAdd(&cnt[key], 1);
    }
}

__global__ __launch_bounds__(1024) void scan_kernel(
    const int* __restrict__ cnt, int n, int* __restrict__ offs, int* __restrict__ cur)
{
    __shared__ int part[1024];
    const int tid = threadIdx.x;
    const int chunk = (n + 1023) >> 10;
    const int lo = min(n, tid * chunk), hi = min(n, lo + chunk);
    int s = 0;
    for (int i = lo; i < hi; ++i) s += cnt[i];
    part[tid] = s;
    __syncthreads();
    for (int d = 1; d < 1024; d <<= 1) {
        const int t = (tid >= d) ? part[tid - d] : 0;
        __syncthreads();
        part[tid] += t;
        __syncthreads();
    }
    int run = part[tid] - s;
    for (int i = lo; i < hi; ++i) {
        const int cv = cnt[i];
        offs[i] = run; cur[i] = run; run += cv;
    }
    if (tid == 1023) offs[n] = run;
}

template<int WITHK>
__global__ __launch_bounds__(256) void bucket_kernel(
    const int* __restrict__ gat, const int* __restrict__ scat, int E, int SH,
    int packSH, int kSH, int* __restrict__ cur, unsigned* __restrict__ recs)
{
    const int k = blockIdx.y;
    const int* g = gat + (size_t)k * E;
    const int* d = scat + (size_t)k * E;
    for (int e = blockIdx.x * 256 + threadIdx.x; e < E; e += gridDim.x * 256) {
        const int dv = d[e];
        int key = dv >> SH;
        if (WITHK) key = key * 27 + k;
        unsigned rec = (unsigned)g[e] | ((unsigned)(dv & ((1 << SH) - 1)) << packSH);
        if (!WITHK) rec |= (unsigned)k << kSH;
        const int pos = atomicAdd(&cur[key], 1);
        recs[pos] = rec;
    }
}

// ===========================================================================
// Scatter conv (baseline structure) + 8-edge groups + 1-deep register
// prefetch: group n+1's src/x loads are issued BEFORE group n's FMA block,
// so gather latency hides under ~2x the FMA work of the old 4-edge version.
// W staged once per block (k = blockIdx.y). Global atomics kept.
// ===========================================================================
template<int CHUNKS>
__global__ __launch_bounds__(256) void conv_scatter8(
    const float* __restrict__ x, const float* __restrict__ W,
    const int* __restrict__ src, const int* __restrict__ dst,
    float* __restrict__ acc, int E)
{
    constexpr int CIN = CHUNKS * 64;
    __shared__ float Wl[CIN * 64];
    __shared__ float xl[4][8 * CIN];
    const int k   = blockIdx.y;
    const int tid = threadIdx.x;
    const int w   = tid >> 6;
    const int c   = tid & 63;

    const float* Wk = W + (size_t)k * (CIN * 64);
    for (int i = tid * 4; i < CIN * 64; i += 1024)
        *(float4*)&Wl[i] = *(const float4*)&Wk[i];
    __syncthreads();

    const int* srcK = src + (size_t)k * E;
    const int* dstK = dst + (size_t)k * E;
    float* xw = xl[w];
    const int stride = gridDim.x * 32;
    const int last = E - 1;

    int e0 = blockIdx.x * 32 + w * 8;
    if (e0 < E) {
        int   q[8];
        float g[8][CHUNKS];
        #pragma unroll
        for (int j = 0; j < 8; ++j) q[j] = srcK[min(e0 + j, last)];
        #pragma unroll
        for (int j = 0; j < 8; ++j)
            #pragma unroll
            for (int h = 0; h < CHUNKS; ++h)
                g[j][h] = x[(size_t)q[j] * CIN + h * 64 + c];

        while (e0 < E) {
            const int ne = E - e0;
            int d[8];
            #pragma unroll
            for (int j = 0; j < 8; ++j) d[j] = dstK[min(e0 + j, last)];
            // commit current gather group to LDS (waits only on g-loads,
            // which have been in flight since before the previous FMA block)
            #pragma unroll
            for (int j = 0; j < 8; ++j)
                #pragma unroll
                for (int h = 0; h < CHUNKS; ++h)
                    xw[j * CIN + h * 64 + c] = g[j][h];
            const int en = e0 + stride;
            if (en < E) {   // issue next group's loads before the FMA block
                #pragma unroll
                for (int j = 0; j < 8; ++j) q[j] = srcK[min(en + j, last)];
                #pragma unroll
                for (int j = 0; j < 8; ++j)
                    #pragma unroll
                    for (int h = 0; h < CHUNKS; ++h)
                        g[j][h] = x[(size_t)q[j] * CIN + h * 64 + c];
            }
            __builtin_amdgcn_wave_barrier();

            float a[8] = {0.f, 0.f, 0.f, 0.f, 0.f, 0.f, 0.f, 0.f};
            #pragma unroll 4
            for (int i = 0; i < CIN; i += 4) {
                const float w0 = Wl[(i + 0) * 64 + c];
                const float w1 = Wl[(i + 1) * 64 + c];
                const float w2 = Wl[(i + 2) * 64 + c];
                const float w3 = Wl[(i + 3) * 64 + c];
                #pragma unroll
                for (int j = 0; j < 8; ++j) {
                    const float4 xv = *(const float4*)&xw[j * CIN + i];
                    a[j] = fmaf(xv.w, w3, fmaf(xv.z, w2, fmaf(xv.y, w1, fmaf(xv.x, w0, a[j]))));
                }
            }
            __builtin_amdgcn_wave_barrier();

            #pragma unroll
            for (int j = 0; j < 8; ++j)
                if (j < ne) atomicAdd(&acc[(size_t)d[j] * 64 + c], a[j]);
            e0 = en;
        }
    }
}

// ---------------------------------------------------------------------------
// Cin=1 up-conv, gather-style (R2-R4 verified): block owns 128 fine rows;
// all of W_up in LDS; LDS atomics (lane=channel, conflict-free); each output
// row written exactly once; fused per-channel stats epilogue.
// ---------------------------------------------------------------------------
__global__ __launch_bounds__(256) void conv_up_gather(
    const float* __restrict__ s1, const float* __restrict__ Wup,
    const unsigned* __restrict__ recs, const int* __restrict__ offs,
    float* __restrict__ outb, int Nout, float* __restrict__ st)
{
    __shared__ float acc[128 * 64];          // 32 KB
    __shared__ float Wl[27 * 64];            // 6.9 KB
    __shared__ float red[512];               // 2 KB
    const int p   = blockIdx.x;
    const int tid = threadIdx.x;
    const int w   = tid >> 6;
    const int c   = tid & 63;

    const float4 z = {0.f, 0.f, 0.f, 0.f};
    for (int i = tid * 4; i < 128 * 64; i += 1024) *(float4*)&acc[i] = z;
    for (int i = tid; i < 27 * 64; i += 256) Wl[i] = Wup[i];
    __syncthreads();

    const int lo = offs[p], hi = offs[p + 1];
    int e0 = lo + w * 4;
    if (e0 < hi) {
        const int last = hi - 1;
        unsigned q0 = recs[e0];
        unsigned q1 = recs[min(e0 + 1, last)];
        unsigned q2 = recs[min(e0 + 2, last)];
        unsigned q3 = recs[min(e0 + 3, last)];
        float v0 = s1[q0 & 0xFFFFu];
        float v1 = s1[q1 & 0xFFFFu];
        float v2 = s1[q2 & 0xFFFFu];
        float v3 = s1[q3 & 0xFFFFu];
        while (e0 < hi) {
            const int ne = hi - e0;
            const unsigned d0 = q0, d1 = q1, d2 = q2, d3 = q3;
            const float u0 = v0, u1 = v1, u2 = v2, u3 = v3;
            const int en = e0 + 16;
            if (en < hi) {
                const int l2 = hi - 1;
                q0 = recs[en];
                q1 = recs[min(en + 1, l2)];
                q2 = recs[min(en + 2, l2)];
                q3 = recs[min(en + 3, l2)];
                v0 = s1[q0 & 0xFFFFu];
                v1 = s1[q1 & 0xFFFFu];
                v2 = s1[q2 & 0xFFFFu];
                v3 = s1[q3 & 0xFFFFu];
            }
            atomicAdd(&acc[(int)((d0 >> 16) & 127u) * 64 + c], u0 * Wl[(int)(d0 >> 23) * 64 + c]);
            if (ne > 1) atomicAdd(&acc[(int)((d1 >> 16) & 127u) * 64 + c], u1 * Wl[(int)(d1 >> 23) * 64 + c]);
            if (ne > 2) atomicAdd(&acc[(int)((d2 >> 16) & 127u) * 64 + c], u2 * Wl[(int)(d2 >> 23) * 64 + c]);
            if (ne > 3) atomicAdd(&acc[(int)((d3 >> 16) & 127u) * 64 + c], u3 * Wl[(int)(d3 >> 23) * 64 + c]);
            e0 = en;
        }
    }
    __syncthreads();

    const int base = p * 128;
    for (int i = tid; i < 128 * 16; i += 256) {
        const int row = base + (i >> 4);
        if (row < Nout)
            *(float4*)&outb[(size_t)row * 64 + (i & 15) * 4] = *(const float4*)&acc[i * 4];
    }

    float s = 0.f, q = 0.f;
    #pragma unroll
    for (int rr = 0; rr < 32; ++rr) {
        const float v = acc[(w * 32 + rr) * 64 + c];
        s += v;
        q = fmaf(v, v, q);
    }
    red[tid] = s; red[256 + tid] = q;
    __syncthreads();
    if (tid < 64) {
        atomicAdd(&st[c],      red[c] + red[64 + c] + red[128 + c] + red[192 + c]);
        atomicAdd(&st[64 + c], red[256 + c] + red[320 + c] + red[384 + c] + red[448 + c]);
    }
}

// ---------------------------------------------------------------------------
// Cout=1 conv: acc1[dst] += dot(s[src,:64], W_sum[k,:,0]). Thread-per-edge.
// ---------------------------------------------------------------------------
__global__ __launch_bounds__(256) void conv_sum_kernel(
    const float* __restrict__ s, const float* __restrict__ Wsum,
    const int* __restrict__ src, const int* __restrict__ dst,
    float* __restrict__ acc1, int E)
{
    const int k = blockIdx.y;
    __shared__ float Wl[64];
    if (threadIdx.x < 64) Wl[threadIdx.x] = Wsum[k * 64 + threadIdx.x];
    __syncthreads();
    for (int e = blockIdx.x * 256 + threadIdx.x; e < E; e += gridDim.x * 256) {
        const int si = src[(size_t)k * E + e];
        const float4* row = (const float4*)(s + (size_t)si * 64);
        float acc = 0.f;
        #pragma unroll
        for (int q = 0; q < 16; ++q) {
            const float4 v = row[q];
            acc = fmaf(v.x, Wl[q * 4 + 0], acc);
            acc = fmaf(v.y, Wl[q * 4 + 1], acc);
            acc = fmaf(v.z, Wl[q * 4 + 2], acc);
            acc = fmaf(v.w, Wl[q * 4 + 3], acc);
        }
        atomicAdd(&acc1[dst[(size_t)k * E + e]], acc);
    }
}

// ---------------------------------------------------------------------------
__global__ __launch_bounds__(256) void stats64(
    const float* __restrict__ x, int N, float* __restrict__ st)
{
    const int c  = threadIdx.x & 63;
    const int rg = threadIdx.x >> 6;
    float s = 0.f, q = 0.f;
    for (int r = blockIdx.x * 4 + rg; r < N; r += gridDim.x * 4) {
        const float v = x[(size_t)r * 64 + c];
        s += v;
        q = fmaf(v, v, q);
    }
    __shared__ float ls[256], lq[256];
    ls[threadIdx.x] = s; lq[threadIdx.x] = q;
    __syncthreads();
    if (threadIdx.x < 64) {
        s = ls[c] + ls[64 + c] + ls[128 + c] + ls[192 + c];
        q = lq[c] + lq[64 + c] + lq[128 + c] + lq[192 + c];
        atomicAdd(&st[c], s);
        atomicAdd(&st[64 + c], q);
    }
}

__global__ __launch_bounds__(256) void stats1(
    const float* __restrict__ x, int N, float* __restrict__ st)
{
    float s = 0.f, q = 0.f;
    for (int i = blockIdx.x * 256 + threadIdx.x; i < N; i += gridDim.x * 256) {
        const float v = x[i];
        s += v;
        q = fmaf(v, v, q);
    }
    __shared__ float ls[256], lq[256];
    ls[threadIdx.x] = s; lq[threadIdx.x] = q;
    __syncthreads();
    for (int off = 128; off > 0; off >>= 1) {
        if (threadIdx.x < off) {
            ls[threadIdx.x] += ls[threadIdx.x + off];
            lq[threadIdx.x] += lq[threadIdx.x + off];
        }
        __syncthreads();
    }
    if (threadIdx.x == 0) { atomicAdd(&st[0], ls[0]); atomicAdd(&st[1], lq[0]); }
}

// ---------------------------------------------------------------------------
// In-place BN + activation (ACT 0=LeakyReLU, 1=sigmoid), optional += add.
// ---------------------------------------------------------------------------
template<int ACT>
__global__ __launch_bounds__(256) void apply_bn(
    float* __restrict__ x, const float* __restrict__ st, int N, float invN,
    const float* __restrict__ gam, const float* __restrict__ bet,
    const float* __restrict__ add)
{
    __shared__ float sc[64], sh[64];
    if (threadIdx.x < 64) {
        const int c = threadIdx.x;
        const float m = st[c] * invN;
        const float v = st[64 + c] * invN - m * m;
        const float s = rsqrtf(v + EPS) * gam[c];
        sc[c] = s;
        sh[c] = bet[c] - m * s;
    }
    __syncthreads();
    const size_t n = (size_t)N * 64;
    for (size_t i = (size_t)blockIdx.x * 256 + threadIdx.x; i < n;
         i += (size_t)gridDim.x * 256) {
        const int c = (int)(i & 63);
        float y = fmaf(x[i], sc[c], sh[c]);
        if (ACT == 0) y = (y >= 0.f) ? y : SLOPE * y;
        else          y = 1.f / (1.f + __expf(-y));
        if (add) y += add[i];
        x[i] = y;
    }
}

__global__ __launch_bounds__(256) void apply_bn1(
    float* __restrict__ x, const float* __restrict__ st, int N, float invN,
    const float* __restrict__ gam, const float* __restrict__ bet)
{
    const float m  = st[0] * invN;
    const float v  = st[1] * invN - m * m;
    const float s  = rsqrtf(v + EPS) * gam[0];
    const float sh = bet[0] - m * s;
    for (int i = blockIdx.x * 256 + threadIdx.x; i < N; i += gridDim.x * 256) {
        const float y = fmaf(x[i], s, sh);
        x[i] = (y >= 0.f) ? y : SLOPE * y;
    }
}

// ---------------------------------------------------------------------------
extern "C" void kernel_launch(void* const* d_in, const int* in_sizes, int n_in,
                              void* d_out, int out_size, void* d_ws, size_t ws_size,
                              hipStream_t stream)
{
    const float* gate     = (const float*)d_in[0];
    const float* shortcut = (const float*)d_in[1];
    const int*   src_down = (const int*)d_in[2];
    const int*   dst_down = (const int*)d_in[3];
    const int*   src_g    = (const int*)d_in[4];
    const int*   dst_g    = (const int*)d_in[5];
    const float* W_sc     = (const float*)d_in[6];
    const float* W_g      = (const float*)d_in[8];
    const float* W_gu     = (const float*)d_in[10];
    const float* W_sum    = (const float*)d_in[12];
    const float* W_up     = (const float*)d_in[13];
    const float* gam_sc   = (const float*)d_in[15];
    const float* bet_sc   = (const float*)d_in[16];
    const float* gam_g    = (const float*)d_in[17];
    const float* bet_g    = (const float*)d_in[18];
    const float* gam_gu   = (const float*)d_in[19];
    const float* bet_gu   = (const float*)d_in[20];
    const float* gam_sum  = (const float*)d_in[21];
    const float* bet_sum  = (const float*)d_in[22];
    const float* gam_up   = (const float*)d_in[23];
    const float* bet_up   = (const float*)d_in[24];

    const int K   = 27;
    const int Nc  = in_sizes[0] / 128;   // 60000
    const int Nf  = in_sizes[1] / 64;    // 200000
    const int Ekd = in_sizes[2] / K;     // 40000
    const int Ekg = in_sizes[4] / K;     // 25000

    const int SHF = 7,  RF = 128;        // fine range: 128 rows (32 KB LDS acc)
    const int NRF = (Nf + RF - 1) / RF;  // 1563 bins (k folded into record)
    const int NBF = NRF;

    float* A  = (float*)d_ws;            // acc_theta -> theta
    float* B  = A + (size_t)Nc * 64;     // acc_phi   -> phi
    float* C  = B + (size_t)Nc * 64;     // acc_phi2  -> s
    float* D  = C + (size_t)Nc * 64;     // acc_s1    -> s1
    float* ST = D + Nc;                  // stats: 640 floats
    int* cnt4 = (int*)(ST + 640);
    int* off4 = cnt4 + NBF;
    int* cur4 = off4 + NBF + 1;
    unsigned* rec4 = (unsigned*)(cur4 + NBF);   // K*Ekd records (~4.3 MB)

    const size_t zeroBytes = ((size_t)Nc * 64 * 3 + (size_t)Nc + 640) * sizeof(float)
                           + (size_t)NBF * sizeof(int);   // A..D, ST, cnt4
    hipMemsetAsync(d_ws, 0, zeroBytes, stream);
    float* out = (float*)d_out;          // written exactly once by conv_up_gather

    const dim3 blk(256);

    // ---- sort down-edges by fine output range (for conv_up only) ----
    hist_kernel<0><<<dim3(64, K), blk, 0, stream>>>(src_down, Ekd, SHF, cnt4);
    scan_kernel<<<1, 1024, 0, stream>>>(cnt4, NBF, off4, cur4);
    bucket_kernel<0><<<dim3(64, K), blk, 0, stream>>>(dst_down, src_down, Ekd, SHF, 16, 23, cur4, rec4);

    // theta = leaky(bn(sconv(shortcut, W_sc, src_down->dst_down)))
    conv_scatter8<1><<<dim3(64, K), blk, 0, stream>>>(shortcut, W_sc, src_down, dst_down, A, Ekd);
    // phi_raw = sconv(gate, W_g, src_g->dst_g)
    conv_scatter8<2><<<dim3(64, K), blk, 0, stream>>>(gate, W_g, src_g, dst_g, B, Ekg);

    stats64<<<256, blk, 0, stream>>>(A, Nc, ST + 0);
    stats64<<<256, blk, 0, stream>>>(B, Nc, ST + 128);
    apply_bn<0><<<1024, blk, 0, stream>>>(A, ST + 0,   Nc, 1.0f / Nc, gam_sc, bet_sc, nullptr);
    apply_bn<0><<<1024, blk, 0, stream>>>(B, ST + 128, Nc, 1.0f / Nc, gam_g,  bet_g,  nullptr);

    // phi = leaky(bn(sconv(phi, W_gu, dst_g->src_g)))  (transposed index pairs)
    conv_scatter8<1><<<dim3(64, K), blk, 0, stream>>>(B, W_gu, dst_g, src_g, C, Ekg);
    stats64<<<256, blk, 0, stream>>>(C, Nc, ST + 256);
    // s = leaky(bn(C)) + theta
    apply_bn<0><<<1024, blk, 0, stream>>>(C, ST + 256, Nc, 1.0f / Nc, gam_gu, bet_gu, A);

    // s1 = leaky(bn(sconv(s, W_sum, src_g->dst_g)))   (Cout = 1)
    conv_sum_kernel<<<dim3(32, K), blk, 0, stream>>>(C, W_sum, src_g, dst_g, D, Ekg);
    stats1<<<256, blk, 0, stream>>>(D, Nc, ST + 384);
    apply_bn1<<<256, blk, 0, stream>>>(D, ST + 384, Nc, 1.0f / Nc, gam_sum, bet_sum);

    // out = sigmoid(bn(sconv(s1, W_up, dst_down->src_down)))  (Cin = 1, fine res)
    conv_up_gather<<<NRF, blk, 0, stream>>>(D, W_up, rec4, off4, out, Nf, ST + 512);
    apply_bn<1><<<2048, blk, 0, stream>>>(out, ST + 512, Nf, 1.0f / Nf, gam_up, bet_up, nullptr);
}